// Round 14
// baseline (121.441 us; speedup 1.0000x reference)
//
#include <hip/hip_runtime.h>
#include <hip/hip_bf16.h>
#include <math.h>

#define D_MODEL 512
#define D_FF    2048
#define NBATCH  2
#define NSEQ    384
#define NROWS   (NBATCH * NSEQ)
#define LN_EPS  1e-6f

typedef __attribute__((ext_vector_type(8))) short short8;
typedef __attribute__((ext_vector_type(4))) short short4v;
typedef __attribute__((ext_vector_type(4))) float f32x4;
typedef __hip_bfloat16 bf16;

static __device__ __forceinline__ short bfb(float x) {
    bf16 h = __float2bfloat16(x);
    return *reinterpret_cast<short*>(&h);
}

#define MFMA16(a, b, c) __builtin_amdgcn_mfma_f32_16x16x32_bf16((a), (b), (c), 0, 0, 0)

// ---------------------------------------------------------------------------
// Kernel 1: fused prep. Blocks 0..3071: weight transpose W[K][N]f32->Wt[N][K]bf16.
// Blocks 3072..3839: embed+PE row (native trig).
// ---------------------------------------------------------------------------
__global__ __launch_bounds__(256) void prep_kernel(
    const int* __restrict__ tokens, const float* __restrict__ emb,
    const float* __restrict__ Wq, const float* __restrict__ Wk,
    const float* __restrict__ Wv, const float* __restrict__ Wo,
    const float* __restrict__ W1, const float* __restrict__ W2,
    bf16* __restrict__ wqt, bf16* __restrict__ wkt, bf16* __restrict__ wvt,
    bf16* __restrict__ wot, bf16* __restrict__ w1t, bf16* __restrict__ w2t,
    float* __restrict__ x, bf16* __restrict__ xb)
{
    __shared__ float tile[32][33];
    int t = blockIdx.x;

    if (t < 3072) {
        const float* W; bf16* Wt; int K, N, bx, by;
        if (t < 1024) {
            int w = t >> 8, rem = t & 255;
            W  = (w == 0) ? Wq  : (w == 1) ? Wk  : (w == 2) ? Wv  : Wo;
            Wt = (w == 0) ? wqt : (w == 1) ? wkt : (w == 2) ? wvt : wot;
            K = 512; N = 512; bx = rem & 15; by = rem >> 4;
        } else if (t < 2048) {
            int rem = t - 1024;
            W = W1; Wt = w1t; K = 512; N = 2048; bx = rem & 63; by = rem >> 6;
        } else {
            int rem = t - 2048;
            W = W2; Wt = w2t; K = 2048; N = 512; bx = rem & 15; by = rem >> 4;
        }
        int tx = threadIdx.x & 31, ty = threadIdx.x >> 5;
        #pragma unroll
        for (int r = ty; r < 32; r += 8)
            tile[r][tx] = W[(size_t)(by * 32 + r) * N + bx * 32 + tx];
        __syncthreads();
        #pragma unroll
        for (int r = ty; r < 32; r += 8)
            Wt[(size_t)(bx * 32 + r) * K + by * 32 + tx] = __float2bfloat16(tile[tx][r]);
    } else {
        int row = t - 3072;              // b*NSEQ + n
        int n   = row % NSEQ;
        int tok = tokens[row];
        const float sqrtD = 22.627416997969522f; // sqrt(512)
        const float ESC   = 0.02595256324130752f; // log2(10000)/512
        for (int d = threadIdx.x; d < D_MODEL; d += 256) {
            float e   = emb[tok * D_MODEL + d] * sqrtD;
            float ang = (float)n * __builtin_amdgcn_exp2f(-(float)(d & ~1) * ESC);
            float pe  = (d & 1) ? __cosf(ang) : __sinf(ang);
            float val = e + pe;
            x [(size_t)row * D_MODEL + d] = val;
            xb[(size_t)row * D_MODEL + d] = __float2bfloat16(val);
        }
    }
}

// ---------------------------------------------------------------------------
// Kernel 2: fused QKV MFMA GEMM (no LDS). blockIdx.z selects q/k/v.
//  z=0: aexp = exp(2*(x@Wq+bq)); z=1: bexp = exp(2*(x@Wk+bk));
//  z=2: vT[b][d][j] = bf16(x@Wv+bv)   (transposed for PV MFMA B-operand)
// ---------------------------------------------------------------------------
__global__ __launch_bounds__(256) void qkv_mfma_kernel(
    const bf16* __restrict__ A,
    const bf16* __restrict__ wqt, const bf16* __restrict__ wkt, const bf16* __restrict__ wvt,
    const float* __restrict__ bq, const float* __restrict__ bk, const float* __restrict__ bv,
    float* __restrict__ aexp, float* __restrict__ bexp, bf16* __restrict__ vT)
{
    int z = blockIdx.z;
    const bf16*  Wt   = (z == 0) ? wqt : (z == 1) ? wkt : wvt;
    const float* bias = (z == 0) ? bq  : (z == 1) ? bk  : bv;

    int lane = threadIdx.x & 63, wid = threadIdx.x >> 6;
    int rowBase = blockIdx.y * 32 + (wid >> 1) * 16;
    int colBase = blockIdx.x * 64 + (wid & 1) * 32;

    const bf16* Ap  = A  + (size_t)(rowBase + (lane & 15)) * D_MODEL + ((lane >> 4) << 3);
    const bf16* Bp0 = Wt + (size_t)(colBase + (lane & 15)) * D_MODEL + ((lane >> 4) << 3);
    const bf16* Bp1 = Bp0 + (size_t)16 * D_MODEL;

    f32x4 acc0 = {0.f, 0.f, 0.f, 0.f};
    f32x4 acc1 = {0.f, 0.f, 0.f, 0.f};

    #pragma unroll 4
    for (int k0 = 0; k0 < D_MODEL; k0 += 32) {
        short8 a  = *reinterpret_cast<const short8*>(Ap  + k0);
        short8 b0 = *reinterpret_cast<const short8*>(Bp0 + k0);
        short8 b1 = *reinterpret_cast<const short8*>(Bp1 + k0);
        acc0 = MFMA16(a, b0, acc0);
        acc1 = MFMA16(a, b1, acc1);
    }

    int crow = rowBase + ((lane >> 4) << 2);
    int ccol = colBase + (lane & 15);

    if (z < 2) {
        float* C = (z == 0) ? aexp : bexp;
        #pragma unroll
        for (int r = 0; r < 4; ++r) {
            int row = crow + r;
            #pragma unroll
            for (int j = 0; j < 2; ++j) {
                int col = ccol + j * 16;
                float val = (j == 0 ? acc0[r] : acc1[r]) + bias[col];
                C[(size_t)row * D_MODEL + col] = __expf(2.0f * val);
            }
        }
    } else {
        int bb = crow / NSEQ;
        int jr = crow - bb * NSEQ;
        #pragma unroll
        for (int j = 0; j < 2; ++j) {
            int col = ccol + j * 16;
            short4v pk;
            #pragma unroll
            for (int r = 0; r < 4; ++r)
                pk[r] = bfb((j == 0 ? acc0[r] : acc1[r]) + bias[col]);
            size_t idx = ((size_t)bb * D_MODEL + col) * NSEQ + jr;
            *reinterpret_cast<short4v*>((short*)vT + idx) = pk;
        }
    }
}

// ---------------------------------------------------------------------------
// Kernel 3: score v4 — TI=2 occupancy rebuild.
// u_ij = sum_d sv_d * rcp(a_id*b_jd+1) (pairwise-rcp); E = exp(u) unnormalized;
// Sp[row][quarter] = partial sums. Deferred batch reduction: 3 t6-iters (12
// u-values) accumulate in regs, then 12 independent 6-stage butterflies.
// TI=2 rows/block, quarter-j: grid (NROWS/2, 4) = 1536 blocks; 512 thr.
// __launch_bounds__(512,4): >=4 waves/EU -> VGPR<=128 -> >=2 blocks/CU.
// ---------------------------------------------------------------------------
__global__ __launch_bounds__(512, 4) void score_kernel(
    const float* __restrict__ aexp, const float* __restrict__ bexp,
    const float* __restrict__ scale, bf16* __restrict__ E,
    float* __restrict__ Sp)
{
    int ig   = blockIdx.x;
    int qt   = blockIdx.y;
    int row0 = ig * 2;
    int b    = row0 / NSEQ;
    int tid  = threadIdx.x;
    int lane = tid & 63, wid = tid >> 6;

    __shared__ float sred[8][2];

    const float* ap = aexp + (size_t)row0 * D_MODEL + lane * 8;
    float a[2][8];
    #pragma unroll
    for (int r = 0; r < 2; ++r) {
        float4 A0 = *(const float4*)(ap + (size_t)r * D_MODEL);
        float4 A1 = *(const float4*)(ap + (size_t)r * D_MODEL + 4);
        a[r][0]=A0.x; a[r][1]=A0.y; a[r][2]=A0.z; a[r][3]=A0.w;
        a[r][4]=A1.x; a[r][5]=A1.y; a[r][6]=A1.z; a[r][7]=A1.w;
    }
    float4 S0 = *(const float4*)(scale + lane * 8);
    float4 S1 = *(const float4*)(scale + lane * 8 + 4);
    float sv[8] = {-2.0f*S0.x,-2.0f*S0.y,-2.0f*S0.z,-2.0f*S0.w,
                   -2.0f*S1.x,-2.0f*S1.y,-2.0f*S1.z,-2.0f*S1.w};

    const float* kb = bexp + (size_t)b * NSEQ * D_MODEL + lane * 8;
    int jb = qt * 96 + wid;

    float es[2] = {0.f, 0.f};

    #pragma unroll
    for (int half = 0; half < 2; ++half) {
        float uacc[3][2][2];
        #pragma unroll
        for (int t3 = 0; t3 < 3; ++t3)
            #pragma unroll
            for (int r = 0; r < 2; ++r) {
                uacc[t3][r][0] = 0.f; uacc[t3][r][1] = 0.f;
            }

        // ---- compute partials for 3 iterations (no reduction yet)
        #pragma unroll
        for (int t3 = 0; t3 < 3; ++t3) {
            int t6 = half * 3 + t3;
            int j0 = jb + t6 * 16;
            int j1 = j0 + 8;
            const float4* kp0 = (const float4*)(kb + (size_t)j0 * D_MODEL);
            const float4* kp1 = (const float4*)(kb + (size_t)j1 * D_MODEL);
            float4 xa = kp0[0], xc = kp0[1];
            float4 ya = kp1[0], yc = kp1[1];
            float b0[8] = {xa.x,xa.y,xa.z,xa.w,xc.x,xc.y,xc.z,xc.w};
            float b1[8] = {ya.x,ya.y,ya.z,ya.w,yc.x,yc.y,yc.z,yc.w};

            #pragma unroll
            for (int up = 0; up < 4; ++up) {
                int d0 = up * 2, d1 = d0 + 1;
                #pragma unroll
                for (int js = 0; js < 2; ++js) {
                    float xx = js ? b1[d0] : b0[d0];
                    float yy = js ? b1[d1] : b0[d1];
                    #pragma unroll
                    for (int r = 0; r < 2; ++r) {
                        float p   = fmaf(a[r][d0], xx, 1.0f);
                        float q   = fmaf(a[r][d1], yy, 1.0f);
                        float num = fmaf(sv[d0], q, sv[d1] * p);
                        uacc[t3][r][js] = fmaf(num, __builtin_amdgcn_rcpf(p * q),
                                               uacc[t3][r][js]);
                    }
                }
            }
        }

        // ---- 12 independent butterflies (6 stages, ILP-hidden)
        #pragma unroll
        for (int off = 1; off < 64; off <<= 1)
            #pragma unroll
            for (int t3 = 0; t3 < 3; ++t3)
                #pragma unroll
                for (int r = 0; r < 2; ++r) {
                    uacc[t3][r][0] += __shfl_xor(uacc[t3][r][0], off, 64);
                    uacc[t3][r][1] += __shfl_xor(uacc[t3][r][1], off, 64);
                }

        // ---- exp + write + es
        #pragma unroll
        for (int t3 = 0; t3 < 3; ++t3) {
            int t6 = half * 3 + t3;
            int j0 = jb + t6 * 16;
            int j1 = j0 + 8;
            #pragma unroll
            for (int r = 0; r < 2; ++r) {
                float e0 = __expf(uacc[t3][r][0]);
                float e1 = __expf(uacc[t3][r][1]);
                if (lane == 0) {
                    E[(size_t)(row0 + r) * NSEQ + j0] = __float2bfloat16(e0);
                    E[(size_t)(row0 + r) * NSEQ + j1] = __float2bfloat16(e1);
                }
                es[r] += e0 + e1;
            }
        }
    }

    if (lane == 0) {
        sred[wid][0] = es[0]; sred[wid][1] = es[1];
    }
    __syncthreads();
    if (tid < 2) {
        float s = 0.0f;
        #pragma unroll
        for (int w = 0; w < 8; ++w) s += sred[w][tid];
        Sp[(size_t)(row0 + tid) * 4 + qt] = s;
    }
}

// ---------------------------------------------------------------------------
// Kernel 4: PV MFMA + normalize: attnb[b,i,d] = (sum_j E[b,i,j] v[b,j,d]) / S_i
// ---------------------------------------------------------------------------
__global__ __launch_bounds__(256) void pv_mfma_kernel(
    const bf16* __restrict__ E, const bf16* __restrict__ vT,
    const float* __restrict__ Sp, bf16* __restrict__ attnb)
{
    int z = blockIdx.z;
    int lane = threadIdx.x & 63, wid = threadIdx.x >> 6;
    int rowBase = blockIdx.y * 32 + (wid >> 1) * 16;
    int colBase = blockIdx.x * 64 + (wid & 1) * 32;

    const bf16* Ap  = E  + ((size_t)z * NSEQ + rowBase + (lane & 15)) * NSEQ + ((lane >> 4) << 3);
    const bf16* Bp0 = vT + ((size_t)z * D_MODEL + colBase + (lane & 15)) * NSEQ + ((lane >> 4) << 3);
    const bf16* Bp1 = Bp0 + (size_t)16 * NSEQ;

    f32x4 acc0 = {0.f, 0.f, 0.f, 0.f};
    f32x4 acc1 = {0.f, 0.f, 0.f, 0.f};

    #pragma unroll 4
    for (int k0 = 0; k0 < NSEQ; k0 += 32) {
        short8 a  = *reinterpret_cast<const short8*>(Ap  + k0);
        short8 b0 = *reinterpret_cast<const short8*>(Bp0 + k0);
        short8 b1 = *reinterpret_cast<const short8*>(Bp1 + k0);
        acc0 = MFMA16(a, b0, acc0);
        acc1 = MFMA16(a, b1, acc1);
    }

    int crow = rowBase + ((lane >> 4) << 2);
    int ccol = colBase + (lane & 15);
    #pragma unroll
    for (int r = 0; r < 4; ++r) {
        int grow = z * NSEQ + crow + r;
        float4 sp4 = *(const float4*)(Sp + (size_t)grow * 4);
        float Sinv = 1.0f / (sp4.x + sp4.y + sp4.z + sp4.w);
        #pragma unroll
        for (int j = 0; j < 2; ++j)
            attnb[(size_t)grow * D_MODEL + ccol + j * 16] =
                __float2bfloat16((j == 0 ? acc0[r] : acc1[r]) * Sinv);
    }
}

// ---------------------------------------------------------------------------
// Kernel 5: generic bf16 MFMA GEMM (no LDS): C = A @ Wt^T + bias (+resid)
// (used for Wo projection)
// ---------------------------------------------------------------------------
__global__ __launch_bounds__(256) void mfma_gemm_kernel(
    const bf16* __restrict__ A, const bf16* __restrict__ Wt,
    const float* __restrict__ bias, const float* __restrict__ resid,
    float* __restrict__ Cf, int K, int N)
{
    int lane = threadIdx.x & 63, wid = threadIdx.x >> 6;
    int rowBase = blockIdx.y * 32 + (wid >> 1) * 16;
    int colBase = blockIdx.x * 64 + (wid & 1) * 32;

    const bf16* Ap  = A  + (size_t)(rowBase + (lane & 15)) * K + ((lane >> 4) << 3);
    const bf16* Bp0 = Wt + (size_t)(colBase + (lane & 15)) * K + ((lane >> 4) << 3);
    const bf16* Bp1 = Bp0 + (size_t)16 * K;

    f32x4 acc0 = {0.f, 0.f, 0.f, 0.f};
    f32x4 acc1 = {0.f, 0.f, 0.f, 0.f};

    #pragma unroll 4
    for (int k0 = 0; k0 < K; k0 += 32) {
        short8 a  = *reinterpret_cast<const short8*>(Ap  + k0);
        short8 b0 = *reinterpret_cast<const short8*>(Bp0 + k0);
        short8 b1 = *reinterpret_cast<const short8*>(Bp1 + k0);
        acc0 = MFMA16(a, b0, acc0);
        acc1 = MFMA16(a, b1, acc1);
    }

    int crow = rowBase + ((lane >> 4) << 2);
    int ccol = colBase + (lane & 15);
    #pragma unroll
    for (int r = 0; r < 4; ++r) {
        int row = crow + r;
        #pragma unroll
        for (int j = 0; j < 2; ++j) {
            int col = ccol + j * 16;
            float val = (j == 0 ? acc0[r] : acc1[r]) + bias[col]
                      + resid[(size_t)row * N + col];
            Cf[(size_t)row * N + col] = val;
        }
    }
}

// ---------------------------------------------------------------------------
// Kernel 6: fused LayerNorm1 + FF-up + ReLU (r13 structure, unchanged).
// ---------------------------------------------------------------------------
__global__ __launch_bounds__(256) void ffup_ln_kernel(
    const float* __restrict__ t1, const float* __restrict__ g1,
    const float* __restrict__ beta1, const bf16* __restrict__ w1t,
    const float* __restrict__ bf1, float* __restrict__ x1,
    bf16* __restrict__ hb)
{
    int rowBase = blockIdx.y * 32;
    int colBase = blockIdx.x * 64;
    int tid  = threadIdx.x;
    int lane = tid & 63, wid = tid >> 6;      // 4 waves

    __shared__ bf16 x1S[32][D_MODEL + 8];

    float4 G0 = *(const float4*)(g1 + lane * 8);
    float4 G1 = *(const float4*)(g1 + lane * 8 + 4);
    float4 B0 = *(const float4*)(beta1 + lane * 8);
    float4 B1 = *(const float4*)(beta1 + lane * 8 + 4);
    float gv[8] = {G0.x,G0.y,G0.z,G0.w,G1.x,G1.y,G1.z,G1.w};
    float bv[8] = {B0.x,B0.y,B0.z,B0.w,B1.x,B1.y,B1.z,B1.w};

    #pragma unroll
    for (int rr = 0; rr < 8; ++rr) {
        int lrow = wid * 8 + rr;
        size_t grow = (size_t)(rowBase + lrow);
        const float* rp = t1 + grow * D_MODEL + lane * 8;
        float4 V0 = *(const float4*)rp;
        float4 V1 = *(const float4*)(rp + 4);
        float v[8] = {V0.x,V0.y,V0.z,V0.w,V1.x,V1.y,V1.z,V1.w};

        float s = ((v[0]+v[1])+(v[2]+v[3])) + ((v[4]+v[5])+(v[6]+v[7]));
        #pragma unroll
        for (int off = 1; off < 64; off <<= 1) s += __shfl_xor(s, off, 64);
        float mu = s * (1.0f / D_MODEL);

        float s2 = 0.0f;
        #pragma unroll
        for (int u = 0; u < 8; ++u) { float d = v[u] - mu; s2 += d * d; }
        #pragma unroll
        for (int off = 1; off < 64; off <<= 1) s2 += __shfl_xor(s2, off, 64);
        float inv = rsqrtf(s2 * (1.0f / D_MODEL) + LN_EPS);

        short4v pk0, pk1;
        float o[8];
        #pragma unroll
        for (int u = 0; u < 8; ++u) {
            o[u] = (v[u] - mu) * inv * gv[u] + bv[u];
            if (u < 4) pk0[u] = bfb(o[u]); else pk1[u - 4] = bfb(o[u]);
        }
        *reinterpret_cast<short4v*>(&x1S[lrow][lane * 8])     = pk0;
        *reinterpret_cast<short4v*>(&x1S[lrow][lane * 8 + 4]) = pk1;
        if (blockIdx.x == 0) {
            float4 w0 = {o[0], o[1], o[2], o[3]};
            float4 w1 = {o[4], o[5], o[6], o[7]};
            *(float4*)(x1 + grow * D_MODEL + lane * 8)     = w0;
            *(float4*)(x1 + grow * D_MODEL + lane * 8 + 4) = w1;
        }
    }
    __syncthreads();

    int wrow = (wid >> 1) * 16;
    int wcol = colBase + (wid & 1) * 32;
    int arow = lane & 15, koff = (lane >> 4) << 3;

    const bf16* Bp0 = w1t + (size_t)(wcol + arow) * D_MODEL + koff;
    const bf16* Bp1 = Bp0 + (size_t)16 * D_MODEL;

    f32x4 acc0 = {0.f, 0.f, 0.f, 0.f};
    f32x4 acc1 = {0.f, 0.f, 0.f, 0.f};

    #pragma unroll 4
    for (int k0 = 0; k0 < D_MODEL; k0 += 32) {
        short8 a  = *reinterpret_cast<const short8*>(&x1S[wrow + arow][k0 + koff]);
        short8 b0 = *reinterpret_cast<const short8*>(Bp0 + k0);
        short8 b1 = *reinterpret_cast<const short8*>(Bp1 + k0);
        acc0 = MFMA16(a, b0, acc0);
        acc1 = MFMA16(a, b1, acc1);
    }

    int crow = rowBase + wrow + ((lane >> 4) << 2);
    int ccol = wcol + (lane & 15);
    #pragma unroll
    for (int r = 0; r < 4; ++r) {
        int row = crow + r;
        #pragma unroll
        for (int j = 0; j < 2; ++j) {
            int col = ccol + j * 16;
            float val = fmaxf((j == 0 ? acc0[r] : acc1[r]) + bf1[col], 0.0f);
            hb[(size_t)row * D_FF + col] = __float2bfloat16(val);
        }
    }
}

// ---------------------------------------------------------------------------
// Kernel 7: FF-down with 2-way K-split (z = K-half). z=0 adds bias+resid -> y0;
// z=1 plain partial -> y1. Combined in LN2.
// ---------------------------------------------------------------------------
__global__ __launch_bounds__(256) void ffdown_kernel(
    const bf16* __restrict__ A, const bf16* __restrict__ Wt,
    const float* __restrict__ bias, const float* __restrict__ resid,
    float* __restrict__ y0, float* __restrict__ y1)
{
    int z = blockIdx.z;
    int kbeg = z * (D_FF / 2);
    int lane = threadIdx.x & 63, wid = threadIdx.x >> 6;
    int rowBase = blockIdx.y * 32 + (wid >> 1) * 16;
    int colBase = blockIdx.x * 64 + (wid & 1) * 32;

    const bf16* Ap  = A  + (size_t)(rowBase + (lane & 15)) * D_FF + kbeg + ((lane >> 4) << 3);
    const bf16* Bp0 = Wt + (size_t)(colBase + (lane & 15)) * D_FF + kbeg + ((lane >> 4) << 3);
    const bf16* Bp1 = Bp0 + (size_t)16 * D_FF;

    f32x4 acc0 = {0.f, 0.f, 0.f, 0.f};
    f32x4 acc1 = {0.f, 0.f, 0.f, 0.f};

    #pragma unroll 4
    for (int k0 = 0; k0 < D_FF / 2; k0 += 32) {
        short8 a  = *reinterpret_cast<const short8*>(Ap  + k0);
        short8 b0 = *reinterpret_cast<const short8*>(Bp0 + k0);
        short8 b1 = *reinterpret_cast<const short8*>(Bp1 + k0);
        acc0 = MFMA16(a, b0, acc0);
        acc1 = MFMA16(a, b1, acc1);
    }

    int crow = rowBase + ((lane >> 4) << 2);
    int ccol = colBase + (lane & 15);
    #pragma unroll
    for (int r = 0; r < 4; ++r) {
        int row = crow + r;
        #pragma unroll
        for (int j = 0; j < 2; ++j) {
            int col = ccol + j * 16;
            float val = (j == 0 ? acc0[r] : acc1[r]);
            if (z == 0) {
                val += bias[col] + resid[(size_t)row * D_MODEL + col];
                y0[(size_t)row * D_MODEL + col] = val;
            } else {
                y1[(size_t)row * D_MODEL + col] = val;
            }
        }
    }
}

// ---------------------------------------------------------------------------
// Kernel 8: LayerNorm over last dim (512); in2 = summed partial.
// ---------------------------------------------------------------------------
__global__ __launch_bounds__(256) void ln_kernel(
    const float* __restrict__ in, const float* __restrict__ in2,
    const float* __restrict__ gamma, const float* __restrict__ beta,
    float* __restrict__ out)
{
    int row = blockIdx.x;
    int tid = threadIdx.x;
    int lane = tid & 63, wid = tid >> 6;
    __shared__ float red[4];

    float v0 = in[(size_t)row * D_MODEL + tid];
    float v1 = in[(size_t)row * D_MODEL + tid + 256];
    if (in2) {
        v0 += in2[(size_t)row * D_MODEL + tid];
        v1 += in2[(size_t)row * D_MODEL + tid + 256];
    }

    float s = v0 + v1;
    #pragma unroll
    for (int off = 32; off; off >>= 1) s += __shfl_xor(s, off, 64);
    if (lane == 0) red[wid] = s;
    __syncthreads();
    if (tid == 0) red[0] = red[0] + red[1] + red[2] + red[3];
    __syncthreads();
    float mu = red[0] * (1.0f / D_MODEL);
    __syncthreads();

    float d0 = v0 - mu, d1 = v1 - mu;
    float s2 = d0 * d0 + d1 * d1;
    #pragma unroll
    for (int off = 32; off; off >>= 1) s2 += __shfl_xor(s2, off, 64);
    if (lane == 0) red[wid] = s2;
    __syncthreads();
    if (tid == 0) red[0] = red[0] + red[1] + red[2] + red[3];
    __syncthreads();
    float var = red[0] * (1.0f / D_MODEL);
    float inv = rsqrtf(var + LN_EPS);

    out[(size_t)row * D_MODEL + tid]       = d0 * inv * gamma[tid] + beta[tid];
    out[(size_t)row * D_MODEL + tid + 256] = d1 * inv * gamma[tid + 256] + beta[tid + 256];
}

// ---------------------------------------------------------------------------
extern "C" void kernel_launch(void* const* d_in, const int* in_sizes, int n_in,
                              void* d_out, int out_size, void* d_ws, size_t ws_size,
                              hipStream_t stream)
{
    const int*   tokens = (const int*)  d_in[0];
    const float* emb    = (const float*)d_in[1];
    const float* Wq     = (const float*)d_in[2];
    const float* bq     = (const float*)d_in[3];
    const float* Wk     = (const float*)d_in[4];
    const float* bk     = (const float*)d_in[5];
    const float* Wv     = (const float*)d_in[6];
    const float* bv     = (const float*)d_in[7];
    const float* ascale = (const float*)d_in[8];
    const float* Wo     = (const float*)d_in[9];
    const float* bo     = (const float*)d_in[10];
    const float* g1     = (const float*)d_in[11];
    const float* beta1  = (const float*)d_in[12];
    const float* W1     = (const float*)d_in[13];
    const float* bf1    = (const float*)d_in[14];
    const float* W2     = (const float*)d_in[15];
    const float* bf2    = (const float*)d_in[16];
    const float* g2     = (const float*)d_in[17];
    const float* beta2  = (const float*)d_in[18];

    float* out = (float*)d_out;
    float* ws  = (float*)d_ws;

    const size_t SZ = (size_t)NROWS * D_MODEL;   // 393216

    float* x0   = ws;            // embed out; Wo resid; then y1 (ffdown z=1)
    float* aexp = ws + 1 * SZ;   // exp(2q); dead after score -> t1 (wo out)
    float* bexp = ws + 2 * SZ;   // exp(2k); dead after score -> x1 (LN1 out)
    float* t1 = aexp;
    float* x1 = bexp;
    float* y0 = x1;              // in-place: thread reads resid then writes
    float* y1 = x0;              // x0 dead after wo

    bf16* x0b   = (bf16*)(ws + 3 * SZ);
    bf16* attnb = x0b + SZ;
    bf16* hb    = attnb + SZ;                        // NROWS * D_FF
    bf16* Eb    = hb + (size_t)NROWS * D_FF;         // 2*384*384
    bf16* vTb   = Eb + (size_t)NBATCH * NSEQ * NSEQ; // 2*512*384
    bf16* wqt   = vTb + (size_t)NBATCH * D_MODEL * NSEQ;
    bf16* wkt   = wqt + (size_t)D_MODEL * D_MODEL;
    bf16* wvt   = wkt + (size_t)D_MODEL * D_MODEL;
    bf16* wot   = wvt + (size_t)D_MODEL * D_MODEL;
    bf16* w1t   = wot + (size_t)D_MODEL * D_MODEL;   // [D_FF][D_MODEL]
    bf16* w2t   = w1t + (size_t)D_MODEL * D_FF;      // [D_MODEL][D_FF]
    float* Sp   = (float*)(w2t + (size_t)D_FF * D_MODEL);  // [NROWS][4]

    // 1. weight transposes + embed/PE
    prep_kernel<<<3072 + NROWS, 256, 0, stream>>>(
        tokens, emb, Wq, Wk, Wv, Wo, W1, W2,
        wqt, wkt, wvt, wot, w1t, w2t, x0, x0b);

    // 2. fused QKV (z: 0->aexp, 1->bexp, 2->vT bf16)
    qkv_mfma_kernel<<<dim3(D_MODEL / 64, NROWS / 32, 3), 256, 0, stream>>>(
        x0b, wqt, wkt, wvt, bq, bk, bv, aexp, bexp, vTb);

    // 3. score v4 (TI=2, 1536 blocks) -> E + Sp
    score_kernel<<<dim3(NROWS / 2, 4), 512, 0, stream>>>(aexp, bexp, ascale, Eb, Sp);

    // 4. PV + normalize -> attnb bf16
    pv_mfma_kernel<<<dim3(D_MODEL / 64, NSEQ / 32, NBATCH), 256, 0, stream>>>(
        Eb, vTb, Sp, attnb);

    // 5. output projection + residual -> t1 f32
    mfma_gemm_kernel<<<dim3(D_MODEL / 64, NROWS / 32), 256, 0, stream>>>(
        attnb, wot, bo, x0, t1, D_MODEL, D_MODEL);

    // 6. fused LN1 + FF-up + ReLU -> hb bf16 (+ x1 f32 from blockIdx.x==0)
    ffup_ln_kernel<<<dim3(D_FF / 64, NROWS / 32), 256, 0, stream>>>(
        t1, g1, beta1, w1t, bf1, x1, hb);

    // 7. FF down, 2-way K-split: y0 = partial+bias+resid (in-place x1), y1 = partial
    ffdown_kernel<<<dim3(D_MODEL / 64, NROWS / 32, 2), 256, 0, stream>>>(
        hb, w2t, bf2, x1, y0, y1);

    // 8. LayerNorm 2 over (y0 + y1) -> out
    ln_kernel<<<NROWS, 256, 0, stream>>>(y0, y1, g2, beta2, out);
}

// Round 15
// 118.870 us; speedup vs baseline: 1.0216x; 1.0216x over previous
//
#include <hip/hip_runtime.h>
#include <hip/hip_bf16.h>
#include <math.h>

#define D_MODEL 512
#define D_FF    2048
#define NBATCH  2
#define NSEQ    384
#define NROWS   (NBATCH * NSEQ)
#define LN_EPS  1e-6f

typedef __attribute__((ext_vector_type(8))) short short8;
typedef __attribute__((ext_vector_type(4))) short short4v;
typedef __attribute__((ext_vector_type(4))) float f32x4;
typedef __hip_bfloat16 bf16;

static __device__ __forceinline__ short bfb(float x) {
    bf16 h = __float2bfloat16(x);
    return *reinterpret_cast<short*>(&h);
}

#define MFMA16(a, b, c) __builtin_amdgcn_mfma_f32_16x16x32_bf16((a), (b), (c), 0, 0, 0)

// ---------------------------------------------------------------------------
// Kernel 1: fused prep. Blocks 0..3071: weight transpose W[K][N]f32->Wt[N][K]bf16.
// Blocks 3072..3839: embed+PE row (native trig).
// ---------------------------------------------------------------------------
__global__ __launch_bounds__(256) void prep_kernel(
    const int* __restrict__ tokens, const float* __restrict__ emb,
    const float* __restrict__ Wq, const float* __restrict__ Wk,
    const float* __restrict__ Wv, const float* __restrict__ Wo,
    const float* __restrict__ W1, const float* __restrict__ W2,
    bf16* __restrict__ wqt, bf16* __restrict__ wkt, bf16* __restrict__ wvt,
    bf16* __restrict__ wot, bf16* __restrict__ w1t, bf16* __restrict__ w2t,
    float* __restrict__ x, bf16* __restrict__ xb)
{
    __shared__ float tile[32][33];
    int t = blockIdx.x;

    if (t < 3072) {
        const float* W; bf16* Wt; int K, N, bx, by;
        if (t < 1024) {
            int w = t >> 8, rem = t & 255;
            W  = (w == 0) ? Wq  : (w == 1) ? Wk  : (w == 2) ? Wv  : Wo;
            Wt = (w == 0) ? wqt : (w == 1) ? wkt : (w == 2) ? wvt : wot;
            K = 512; N = 512; bx = rem & 15; by = rem >> 4;
        } else if (t < 2048) {
            int rem = t - 1024;
            W = W1; Wt = w1t; K = 512; N = 2048; bx = rem & 63; by = rem >> 6;
        } else {
            int rem = t - 2048;
            W = W2; Wt = w2t; K = 2048; N = 512; bx = rem & 15; by = rem >> 4;
        }
        int tx = threadIdx.x & 31, ty = threadIdx.x >> 5;
        #pragma unroll
        for (int r = ty; r < 32; r += 8)
            tile[r][tx] = W[(size_t)(by * 32 + r) * N + bx * 32 + tx];
        __syncthreads();
        #pragma unroll
        for (int r = ty; r < 32; r += 8)
            Wt[(size_t)(bx * 32 + r) * K + by * 32 + tx] = __float2bfloat16(tile[tx][r]);
    } else {
        int row = t - 3072;              // b*NSEQ + n
        int n   = row % NSEQ;
        int tok = tokens[row];
        const float sqrtD = 22.627416997969522f; // sqrt(512)
        const float ESC   = 0.02595256324130752f; // log2(10000)/512
        for (int d = threadIdx.x; d < D_MODEL; d += 256) {
            float e   = emb[tok * D_MODEL + d] * sqrtD;
            float ang = (float)n * __builtin_amdgcn_exp2f(-(float)(d & ~1) * ESC);
            float pe  = (d & 1) ? __cosf(ang) : __sinf(ang);
            float val = e + pe;
            x [(size_t)row * D_MODEL + d] = val;
            xb[(size_t)row * D_MODEL + d] = __float2bfloat16(val);
        }
    }
}

// ---------------------------------------------------------------------------
// Kernel 2: fused QKV MFMA GEMM (no LDS). blockIdx.z selects q/k/v.
//  z=0: aexp = exp(2*(x@Wq+bq)); z=1: bexp = exp(2*(x@Wk+bk));
//  z=2: vT[b][d][j] = bf16(x@Wv+bv)   (transposed for PV MFMA B-operand)
// ---------------------------------------------------------------------------
__global__ __launch_bounds__(256) void qkv_mfma_kernel(
    const bf16* __restrict__ A,
    const bf16* __restrict__ wqt, const bf16* __restrict__ wkt, const bf16* __restrict__ wvt,
    const float* __restrict__ bq, const float* __restrict__ bk, const float* __restrict__ bv,
    float* __restrict__ aexp, float* __restrict__ bexp, bf16* __restrict__ vT)
{
    int z = blockIdx.z;
    const bf16*  Wt   = (z == 0) ? wqt : (z == 1) ? wkt : wvt;
    const float* bias = (z == 0) ? bq  : (z == 1) ? bk  : bv;

    int lane = threadIdx.x & 63, wid = threadIdx.x >> 6;
    int rowBase = blockIdx.y * 32 + (wid >> 1) * 16;
    int colBase = blockIdx.x * 64 + (wid & 1) * 32;

    const bf16* Ap  = A  + (size_t)(rowBase + (lane & 15)) * D_MODEL + ((lane >> 4) << 3);
    const bf16* Bp0 = Wt + (size_t)(colBase + (lane & 15)) * D_MODEL + ((lane >> 4) << 3);
    const bf16* Bp1 = Bp0 + (size_t)16 * D_MODEL;

    f32x4 acc0 = {0.f, 0.f, 0.f, 0.f};
    f32x4 acc1 = {0.f, 0.f, 0.f, 0.f};

    #pragma unroll 4
    for (int k0 = 0; k0 < D_MODEL; k0 += 32) {
        short8 a  = *reinterpret_cast<const short8*>(Ap  + k0);
        short8 b0 = *reinterpret_cast<const short8*>(Bp0 + k0);
        short8 b1 = *reinterpret_cast<const short8*>(Bp1 + k0);
        acc0 = MFMA16(a, b0, acc0);
        acc1 = MFMA16(a, b1, acc1);
    }

    int crow = rowBase + ((lane >> 4) << 2);
    int ccol = colBase + (lane & 15);

    if (z < 2) {
        float* C = (z == 0) ? aexp : bexp;
        #pragma unroll
        for (int r = 0; r < 4; ++r) {
            int row = crow + r;
            #pragma unroll
            for (int j = 0; j < 2; ++j) {
                int col = ccol + j * 16;
                float val = (j == 0 ? acc0[r] : acc1[r]) + bias[col];
                C[(size_t)row * D_MODEL + col] = __expf(2.0f * val);
            }
        }
    } else {
        int bb = crow / NSEQ;
        int jr = crow - bb * NSEQ;
        #pragma unroll
        for (int j = 0; j < 2; ++j) {
            int col = ccol + j * 16;
            short4v pk;
            #pragma unroll
            for (int r = 0; r < 4; ++r)
                pk[r] = bfb((j == 0 ? acc0[r] : acc1[r]) + bias[col]);
            size_t idx = ((size_t)bb * D_MODEL + col) * NSEQ + jr;
            *reinterpret_cast<short4v*>((short*)vT + idx) = pk;
        }
    }
}

// ---------------------------------------------------------------------------
// Kernel 3: score v2 (r13 best-known) + __launch_bounds__(512,4) VGPR cap.
// u_ij = sum_d sv_d * rcp(a_id*b_jd+1) (pairwise-rcp); E = exp(u) unnorm;
// Sp[row][quarter] = partial sums. Deferred batch butterflies.
// grid (NROWS/4, 4); 512 thr. Bound: >=4 waves/EU -> VGPR<=128 -> 2 blocks/CU.
// ---------------------------------------------------------------------------
__global__ __launch_bounds__(512, 4) void score_kernel(
    const float* __restrict__ aexp, const float* __restrict__ bexp,
    const float* __restrict__ scale, bf16* __restrict__ E,
    float* __restrict__ Sp)
{
    int ig   = blockIdx.x;
    int qt   = blockIdx.y;
    int row0 = ig * 4;
    int b    = row0 / NSEQ;
    int tid  = threadIdx.x;
    int lane = tid & 63, wid = tid >> 6;

    __shared__ float sred[8][4];

    const float* ap = aexp + (size_t)row0 * D_MODEL + lane * 8;
    float a[4][8];
    #pragma unroll
    for (int r = 0; r < 4; ++r) {
        float4 A0 = *(const float4*)(ap + (size_t)r * D_MODEL);
        float4 A1 = *(const float4*)(ap + (size_t)r * D_MODEL + 4);
        a[r][0]=A0.x; a[r][1]=A0.y; a[r][2]=A0.z; a[r][3]=A0.w;
        a[r][4]=A1.x; a[r][5]=A1.y; a[r][6]=A1.z; a[r][7]=A1.w;
    }
    float4 S0 = *(const float4*)(scale + lane * 8);
    float4 S1 = *(const float4*)(scale + lane * 8 + 4);
    float sv[8] = {-2.0f*S0.x,-2.0f*S0.y,-2.0f*S0.z,-2.0f*S0.w,
                   -2.0f*S1.x,-2.0f*S1.y,-2.0f*S1.z,-2.0f*S1.w};

    const float* kb = bexp + (size_t)b * NSEQ * D_MODEL + lane * 8;
    int jb = qt * 96 + wid;

    float es[4] = {0.f, 0.f, 0.f, 0.f};

    #pragma unroll
    for (int half = 0; half < 2; ++half) {
        float uacc[3][4][2];
        #pragma unroll
        for (int t3 = 0; t3 < 3; ++t3)
            #pragma unroll
            for (int r = 0; r < 4; ++r) {
                uacc[t3][r][0] = 0.f; uacc[t3][r][1] = 0.f;
            }

        #pragma unroll
        for (int t3 = 0; t3 < 3; ++t3) {
            int t6 = half * 3 + t3;
            int j0 = jb + t6 * 16;
            int j1 = j0 + 8;
            const float4* kp0 = (const float4*)(kb + (size_t)j0 * D_MODEL);
            const float4* kp1 = (const float4*)(kb + (size_t)j1 * D_MODEL);
            float4 xa = kp0[0], xc = kp0[1];
            float4 ya = kp1[0], yc = kp1[1];
            float b0[8] = {xa.x,xa.y,xa.z,xa.w,xc.x,xc.y,xc.z,xc.w};
            float b1[8] = {ya.x,ya.y,ya.z,ya.w,yc.x,yc.y,yc.z,yc.w};

            #pragma unroll
            for (int up = 0; up < 4; ++up) {
                int d0 = up * 2, d1 = d0 + 1;
                #pragma unroll
                for (int js = 0; js < 2; ++js) {
                    float xx = js ? b1[d0] : b0[d0];
                    float yy = js ? b1[d1] : b0[d1];
                    #pragma unroll
                    for (int r = 0; r < 4; ++r) {
                        float p   = fmaf(a[r][d0], xx, 1.0f);
                        float q   = fmaf(a[r][d1], yy, 1.0f);
                        float num = fmaf(sv[d0], q, sv[d1] * p);
                        uacc[t3][r][js] = fmaf(num, __builtin_amdgcn_rcpf(p * q),
                                               uacc[t3][r][js]);
                    }
                }
            }
        }

        #pragma unroll
        for (int off = 1; off < 64; off <<= 1)
            #pragma unroll
            for (int t3 = 0; t3 < 3; ++t3)
                #pragma unroll
                for (int r = 0; r < 4; ++r) {
                    uacc[t3][r][0] += __shfl_xor(uacc[t3][r][0], off, 64);
                    uacc[t3][r][1] += __shfl_xor(uacc[t3][r][1], off, 64);
                }

        #pragma unroll
        for (int t3 = 0; t3 < 3; ++t3) {
            int t6 = half * 3 + t3;
            int j0 = jb + t6 * 16;
            int j1 = j0 + 8;
            #pragma unroll
            for (int r = 0; r < 4; ++r) {
                float e0 = __expf(uacc[t3][r][0]);
                float e1 = __expf(uacc[t3][r][1]);
                if (lane == 0) {
                    E[(size_t)(row0 + r) * NSEQ + j0] = __float2bfloat16(e0);
                    E[(size_t)(row0 + r) * NSEQ + j1] = __float2bfloat16(e1);
                }
                es[r] += e0 + e1;
            }
        }
    }

    if (lane == 0) {
        sred[wid][0] = es[0]; sred[wid][1] = es[1];
        sred[wid][2] = es[2]; sred[wid][3] = es[3];
    }
    __syncthreads();
    if (tid < 4) {
        float s = 0.0f;
        #pragma unroll
        for (int w = 0; w < 8; ++w) s += sred[w][tid];
        Sp[(size_t)(row0 + tid) * 4 + qt] = s;
    }
}

// ---------------------------------------------------------------------------
// Kernel 4: PV MFMA + normalize: attnb[b,i,d] = (sum_j E[b,i,j] v[b,j,d]) / S_i
// ---------------------------------------------------------------------------
__global__ __launch_bounds__(256) void pv_mfma_kernel(
    const bf16* __restrict__ E, const bf16* __restrict__ vT,
    const float* __restrict__ Sp, bf16* __restrict__ attnb)
{
    int z = blockIdx.z;
    int lane = threadIdx.x & 63, wid = threadIdx.x >> 6;
    int rowBase = blockIdx.y * 32 + (wid >> 1) * 16;
    int colBase = blockIdx.x * 64 + (wid & 1) * 32;

    const bf16* Ap  = E  + ((size_t)z * NSEQ + rowBase + (lane & 15)) * NSEQ + ((lane >> 4) << 3);
    const bf16* Bp0 = vT + ((size_t)z * D_MODEL + colBase + (lane & 15)) * NSEQ + ((lane >> 4) << 3);
    const bf16* Bp1 = Bp0 + (size_t)16 * NSEQ;

    f32x4 acc0 = {0.f, 0.f, 0.f, 0.f};
    f32x4 acc1 = {0.f, 0.f, 0.f, 0.f};

    #pragma unroll 4
    for (int k0 = 0; k0 < NSEQ; k0 += 32) {
        short8 a  = *reinterpret_cast<const short8*>(Ap  + k0);
        short8 b0 = *reinterpret_cast<const short8*>(Bp0 + k0);
        short8 b1 = *reinterpret_cast<const short8*>(Bp1 + k0);
        acc0 = MFMA16(a, b0, acc0);
        acc1 = MFMA16(a, b1, acc1);
    }

    int crow = rowBase + ((lane >> 4) << 2);
    int ccol = colBase + (lane & 15);
    #pragma unroll
    for (int r = 0; r < 4; ++r) {
        int grow = z * NSEQ + crow + r;
        float4 sp4 = *(const float4*)(Sp + (size_t)grow * 4);
        float Sinv = 1.0f / (sp4.x + sp4.y + sp4.z + sp4.w);
        #pragma unroll
        for (int j = 0; j < 2; ++j)
            attnb[(size_t)grow * D_MODEL + ccol + j * 16] =
                __float2bfloat16((j == 0 ? acc0[r] : acc1[r]) * Sinv);
    }
}

// ---------------------------------------------------------------------------
// Kernel 5: bf16 MFMA GEMM (no LDS): Cf = A @ Wt^T + bias + resid  (Wo)
// ---------------------------------------------------------------------------
__global__ __launch_bounds__(256) void mfma_gemm_kernel(
    const bf16* __restrict__ A, const bf16* __restrict__ Wt,
    const float* __restrict__ bias, const float* __restrict__ resid,
    float* __restrict__ Cf, int K, int N)
{
    int lane = threadIdx.x & 63, wid = threadIdx.x >> 6;
    int rowBase = blockIdx.y * 32 + (wid >> 1) * 16;
    int colBase = blockIdx.x * 64 + (wid & 1) * 32;

    const bf16* Ap  = A  + (size_t)(rowBase + (lane & 15)) * K + ((lane >> 4) << 3);
    const bf16* Bp0 = Wt + (size_t)(colBase + (lane & 15)) * K + ((lane >> 4) << 3);
    const bf16* Bp1 = Bp0 + (size_t)16 * K;

    f32x4 acc0 = {0.f, 0.f, 0.f, 0.f};
    f32x4 acc1 = {0.f, 0.f, 0.f, 0.f};

    #pragma unroll 4
    for (int k0 = 0; k0 < K; k0 += 32) {
        short8 a  = *reinterpret_cast<const short8*>(Ap  + k0);
        short8 b0 = *reinterpret_cast<const short8*>(Bp0 + k0);
        short8 b1 = *reinterpret_cast<const short8*>(Bp1 + k0);
        acc0 = MFMA16(a, b0, acc0);
        acc1 = MFMA16(a, b1, acc1);
    }

    int crow = rowBase + ((lane >> 4) << 2);
    int ccol = colBase + (lane & 15);
    #pragma unroll
    for (int r = 0; r < 4; ++r) {
        int row = crow + r;
        #pragma unroll
        for (int j = 0; j < 2; ++j) {
            int col = ccol + j * 16;
            float val = (j == 0 ? acc0[r] : acc1[r]) + bias[col]
                      + resid[(size_t)row * N + col];
            Cf[(size_t)row * N + col] = val;
        }
    }
}

// ---------------------------------------------------------------------------
// Kernel 6: fused LayerNorm1 + FF-up + ReLU (r13 structure, unchanged).
// ---------------------------------------------------------------------------
__global__ __launch_bounds__(256) void ffup_ln_kernel(
    const float* __restrict__ t1, const float* __restrict__ g1,
    const float* __restrict__ beta1, const bf16* __restrict__ w1t,
    const float* __restrict__ bf1, float* __restrict__ x1,
    bf16* __restrict__ hb)
{
    int rowBase = blockIdx.y * 32;
    int colBase = blockIdx.x * 64;
    int tid  = threadIdx.x;
    int lane = tid & 63, wid = tid >> 6;      // 4 waves

    __shared__ bf16 x1S[32][D_MODEL + 8];

    float4 G0 = *(const float4*)(g1 + lane * 8);
    float4 G1 = *(const float4*)(g1 + lane * 8 + 4);
    float4 B0 = *(const float4*)(beta1 + lane * 8);
    float4 B1 = *(const float4*)(beta1 + lane * 8 + 4);
    float gv[8] = {G0.x,G0.y,G0.z,G0.w,G1.x,G1.y,G1.z,G1.w};
    float bv[8] = {B0.x,B0.y,B0.z,B0.w,B1.x,B1.y,B1.z,B1.w};

    #pragma unroll
    for (int rr = 0; rr < 8; ++rr) {
        int lrow = wid * 8 + rr;
        size_t grow = (size_t)(rowBase + lrow);
        const float* rp = t1 + grow * D_MODEL + lane * 8;
        float4 V0 = *(const float4*)rp;
        float4 V1 = *(const float4*)(rp + 4);
        float v[8] = {V0.x,V0.y,V0.z,V0.w,V1.x,V1.y,V1.z,V1.w};

        float s = ((v[0]+v[1])+(v[2]+v[3])) + ((v[4]+v[5])+(v[6]+v[7]));
        #pragma unroll
        for (int off = 1; off < 64; off <<= 1) s += __shfl_xor(s, off, 64);
        float mu = s * (1.0f / D_MODEL);

        float s2 = 0.0f;
        #pragma unroll
        for (int u = 0; u < 8; ++u) { float d = v[u] - mu; s2 += d * d; }
        #pragma unroll
        for (int off = 1; off < 64; off <<= 1) s2 += __shfl_xor(s2, off, 64);
        float inv = rsqrtf(s2 * (1.0f / D_MODEL) + LN_EPS);

        short4v pk0, pk1;
        float o[8];
        #pragma unroll
        for (int u = 0; u < 8; ++u) {
            o[u] = (v[u] - mu) * inv * gv[u] + bv[u];
            if (u < 4) pk0[u] = bfb(o[u]); else pk1[u - 4] = bfb(o[u]);
        }
        *reinterpret_cast<short4v*>(&x1S[lrow][lane * 8])     = pk0;
        *reinterpret_cast<short4v*>(&x1S[lrow][lane * 8 + 4]) = pk1;
        if (blockIdx.x == 0) {
            float4 w0 = {o[0], o[1], o[2], o[3]};
            float4 w1 = {o[4], o[5], o[6], o[7]};
            *(float4*)(x1 + grow * D_MODEL + lane * 8)     = w0;
            *(float4*)(x1 + grow * D_MODEL + lane * 8 + 4) = w1;
        }
    }
    __syncthreads();

    int wrow = (wid >> 1) * 16;
    int wcol = colBase + (wid & 1) * 32;
    int arow = lane & 15, koff = (lane >> 4) << 3;

    const bf16* Bp0 = w1t + (size_t)(wcol + arow) * D_MODEL + koff;
    const bf16* Bp1 = Bp0 + (size_t)16 * D_MODEL;

    f32x4 acc0 = {0.f, 0.f, 0.f, 0.f};
    f32x4 acc1 = {0.f, 0.f, 0.f, 0.f};

    #pragma unroll 4
    for (int k0 = 0; k0 < D_MODEL; k0 += 32) {
        short8 a  = *reinterpret_cast<const short8*>(&x1S[wrow + arow][k0 + koff]);
        short8 b0 = *reinterpret_cast<const short8*>(Bp0 + k0);
        short8 b1 = *reinterpret_cast<const short8*>(Bp1 + k0);
        acc0 = MFMA16(a, b0, acc0);
        acc1 = MFMA16(a, b1, acc1);
    }

    int crow = rowBase + wrow + ((lane >> 4) << 2);
    int ccol = wcol + (lane & 15);
    #pragma unroll
    for (int r = 0; r < 4; ++r) {
        int row = crow + r;
        #pragma unroll
        for (int j = 0; j < 2; ++j) {
            int col = ccol + j * 16;
            float val = fmaxf((j == 0 ? acc0[r] : acc1[r]) + bf1[col], 0.0f);
            hb[(size_t)row * D_FF + col] = __float2bfloat16(val);
        }
    }
}

// ---------------------------------------------------------------------------
// Kernel 7: FF-down with 2-way K-split (z = K-half). z=0 adds bias+resid -> y0;
// z=1 plain partial -> y1. Combined in LN2.
// ---------------------------------------------------------------------------
__global__ __launch_bounds__(256) void ffdown_kernel(
    const bf16* __restrict__ A, const bf16* __restrict__ Wt,
    const float* __restrict__ bias, const float* __restrict__ resid,
    float* __restrict__ y0, float* __restrict__ y1)
{
    int z = blockIdx.z;
    int kbeg = z * (D_FF / 2);
    int lane = threadIdx.x & 63, wid = threadIdx.x >> 6;
    int rowBase = blockIdx.y * 32 + (wid >> 1) * 16;
    int colBase = blockIdx.x * 64 + (wid & 1) * 32;

    const bf16* Ap  = A  + (size_t)(rowBase + (lane & 15)) * D_FF + kbeg + ((lane >> 4) << 3);
    const bf16* Bp0 = Wt + (size_t)(colBase + (lane & 15)) * D_FF + kbeg + ((lane >> 4) << 3);
    const bf16* Bp1 = Bp0 + (size_t)16 * D_FF;

    f32x4 acc0 = {0.f, 0.f, 0.f, 0.f};
    f32x4 acc1 = {0.f, 0.f, 0.f, 0.f};

    #pragma unroll 4
    for (int k0 = 0; k0 < D_FF / 2; k0 += 32) {
        short8 a  = *reinterpret_cast<const short8*>(Ap  + k0);
        short8 b0 = *reinterpret_cast<const short8*>(Bp0 + k0);
        short8 b1 = *reinterpret_cast<const short8*>(Bp1 + k0);
        acc0 = MFMA16(a, b0, acc0);
        acc1 = MFMA16(a, b1, acc1);
    }

    int crow = rowBase + ((lane >> 4) << 2);
    int ccol = colBase + (lane & 15);
    #pragma unroll
    for (int r = 0; r < 4; ++r) {
        int row = crow + r;
        #pragma unroll
        for (int j = 0; j < 2; ++j) {
            int col = ccol + j * 16;
            float val = (j == 0 ? acc0[r] : acc1[r]);
            if (z == 0) {
                val += bias[col] + resid[(size_t)row * D_MODEL + col];
                y0[(size_t)row * D_MODEL + col] = val;
            } else {
                y1[(size_t)row * D_MODEL + col] = val;
            }
        }
    }
}

// ---------------------------------------------------------------------------
// Kernel 8: LayerNorm over last dim (512); in2 = summed partial.
// ---------------------------------------------------------------------------
__global__ __launch_bounds__(256) void ln_kernel(
    const float* __restrict__ in, const float* __restrict__ in2,
    const float* __restrict__ gamma, const float* __restrict__ beta,
    float* __restrict__ out)
{
    int row = blockIdx.x;
    int tid = threadIdx.x;
    int lane = tid & 63, wid = tid >> 6;
    __shared__ float red[4];

    float v0 = in[(size_t)row * D_MODEL + tid];
    float v1 = in[(size_t)row * D_MODEL + tid + 256];
    if (in2) {
        v0 += in2[(size_t)row * D_MODEL + tid];
        v1 += in2[(size_t)row * D_MODEL + tid + 256];
    }

    float s = v0 + v1;
    #pragma unroll
    for (int off = 32; off; off >>= 1) s += __shfl_xor(s, off, 64);
    if (lane == 0) red[wid] = s;
    __syncthreads();
    if (tid == 0) red[0] = red[0] + red[1] + red[2] + red[3];
    __syncthreads();
    float mu = red[0] * (1.0f / D_MODEL);
    __syncthreads();

    float d0 = v0 - mu, d1 = v1 - mu;
    float s2 = d0 * d0 + d1 * d1;
    #pragma unroll
    for (int off = 32; off; off >>= 1) s2 += __shfl_xor(s2, off, 64);
    if (lane == 0) red[wid] = s2;
    __syncthreads();
    if (tid == 0) red[0] = red[0] + red[1] + red[2] + red[3];
    __syncthreads();
    float var = red[0] * (1.0f / D_MODEL);
    float inv = rsqrtf(var + LN_EPS);

    out[(size_t)row * D_MODEL + tid]       = d0 * inv * gamma[tid] + beta[tid];
    out[(size_t)row * D_MODEL + tid + 256] = d1 * inv * gamma[tid + 256] + beta[tid + 256];
}

// ---------------------------------------------------------------------------
extern "C" void kernel_launch(void* const* d_in, const int* in_sizes, int n_in,
                              void* d_out, int out_size, void* d_ws, size_t ws_size,
                              hipStream_t stream)
{
    const int*   tokens = (const int*)  d_in[0];
    const float* emb    = (const float*)d_in[1];
    const float* Wq     = (const float*)d_in[2];
    const float* bq     = (const float*)d_in[3];
    const float* Wk     = (const float*)d_in[4];
    const float* bk     = (const float*)d_in[5];
    const float* Wv     = (const float*)d_in[6];
    const float* bv     = (const float*)d_in[7];
    const float* ascale = (const float*)d_in[8];
    const float* Wo     = (const float*)d_in[9];
    const float* bo     = (const float*)d_in[10];
    const float* g1     = (const float*)d_in[11];
    const float* beta1  = (const float*)d_in[12];
    const float* W1     = (const float*)d_in[13];
    const float* bf1    = (const float*)d_in[14];
    const float* W2     = (const float*)d_in[15];
    const float* bf2    = (const float*)d_in[16];
    const float* g2     = (const float*)d_in[17];
    const float* beta2  = (const float*)d_in[18];

    float* out = (float*)d_out;
    float* ws  = (float*)d_ws;

    const size_t SZ = (size_t)NROWS * D_MODEL;   // 393216

    float* x0   = ws;            // embed out; Wo resid; then y1 (ffdown z=1)
    float* aexp = ws + 1 * SZ;   // exp(2q); dead after score -> t1 (wo out)
    float* bexp = ws + 2 * SZ;   // exp(2k); dead after score -> x1 (LN1 out)
    float* t1 = aexp;
    float* x1 = bexp;
    float* y0 = x1;              // in-place: thread reads resid then writes
    float* y1 = x0;              // x0 dead after wo

    bf16* x0b   = (bf16*)(ws + 3 * SZ);
    bf16* attnb = x0b + SZ;
    bf16* hb    = attnb + SZ;                        // NROWS * D_FF
    bf16* Eb    = hb + (size_t)NROWS * D_FF;         // 2*384*384
    bf16* vTb   = Eb + (size_t)NBATCH * NSEQ * NSEQ; // 2*512*384
    bf16* wqt   = vTb + (size_t)NBATCH * D_MODEL * NSEQ;
    bf16* wkt   = wqt + (size_t)D_MODEL * D_MODEL;
    bf16* wvt   = wkt + (size_t)D_MODEL * D_MODEL;
    bf16* wot   = wvt + (size_t)D_MODEL * D_MODEL;
    bf16* w1t   = wot + (size_t)D_MODEL * D_MODEL;   // [D_FF][D_MODEL]
    bf16* w2t   = w1t + (size_t)D_MODEL * D_FF;      // [D_MODEL][D_FF]
    float* Sp   = (float*)(w2t + (size_t)D_FF * D_MODEL);  // [NROWS][4]

    // 1. weight transposes + embed/PE
    prep_kernel<<<3072 + NROWS, 256, 0, stream>>>(
        tokens, emb, Wq, Wk, Wv, Wo, W1, W2,
        wqt, wkt, wvt, wot, w1t, w2t, x0, x0b);

    // 2. fused QKV (z: 0->aexp, 1->bexp, 2->vT bf16)
    qkv_mfma_kernel<<<dim3(D_MODEL / 64, NROWS / 32, 3), 256, 0, stream>>>(
        x0b, wqt, wkt, wvt, bq, bk, bv, aexp, bexp, vTb);

    // 3. score v2 + VGPR cap -> E + Sp
    score_kernel<<<dim3(NROWS / 4, 4), 512, 0, stream>>>(aexp, bexp, ascale, Eb, Sp);

    // 4. PV + normalize -> attnb bf16
    pv_mfma_kernel<<<dim3(D_MODEL / 64, NSEQ / 32, NBATCH), 256, 0, stream>>>(
        Eb, vTb, Sp, attnb);

    // 5. output projection + residual -> t1 f32
    mfma_gemm_kernel<<<dim3(D_MODEL / 64, NROWS / 32), 256, 0, stream>>>(
        attnb, wot, bo, x0, t1, D_MODEL, D_MODEL);

    // 6. fused LN1 + FF-up + ReLU -> hb bf16 (+ x1 f32 from blockIdx.x==0)
    ffup_ln_kernel<<<dim3(D_FF / 64, NROWS / 32), 256, 0, stream>>>(
        t1, g1, beta1, w1t, bf1, x1, hb);

    // 7. FF down, 2-way K-split: y0 = partial+bias+resid (in-place x1), y1 = partial
    ffdown_kernel<<<dim3(D_MODEL / 64, NROWS / 32, 2), 256, 0, stream>>>(
        hb, w2t, bf2, x1, y0, y1);

    // 8. LayerNorm 2 over (y0 + y1) -> out
    ln_kernel<<<NROWS, 256, 0, stream>>>(y0, y1, g2, beta2, out);
}